// Round 2
// 552.501 us; speedup vs baseline: 1.0411x; 1.0411x over previous
//
#include <hip/hip_runtime.h>
#include <hip/hip_bf16.h>

#define F_IN 512
#define HID 16
#define NCLS 64
#define NBUCK_MAX 512     // LDS sizing; actual nbuck = ceil(N/256) = 391
#define EPB 8192          // edges per block in hist/partition

// ---------------------------------------------------------------------------
// gemm device part: h0 = relu(x @ W1 + b1), inv0 = 1/max(||h0||,eps), for
// rows [rB, rE). FOUR ROWS PER WAVE ITERATION: the W1 fragment (lane's 8
// rows of W1, re-read from L1) is loaded once and applied to 4 x-rows,
// cutting per-row W1/L1 traffic 32 KB -> 8 KB (gemm1 was TCP-bound).
// Lane owns k in [8*lane, 8*lane+8). Value-halving shuffle tree per row.
// ---------------------------------------------------------------------------
__device__ __forceinline__ void gemm_rows(
    const float* __restrict__ x, const float* __restrict__ W1,
    const float* __restrict__ b1, float* __restrict__ h0,
    float* __restrict__ inv0, int rB, int rE, int wid, int totalWaves, int lane)
{
    float bias = b1[lane & 15];
    const bool s3 = (lane & 8) != 0;
    const bool s2 = (lane & 4) != 0;
    const bool s1 = (lane & 2) != 0;
    const bool s0 = (lane & 1) != 0;

    for (int g = rB + wid * 4; g < rE; g += totalWaves * 4) {
        int r0 = g;
        int r1 = (g + 1 < rE) ? g + 1 : rE - 1;
        int r2 = (g + 2 < rE) ? g + 2 : rE - 1;
        int r3 = (g + 3 < rE) ? g + 3 : rE - 1;

        float xv[4][8];
        {
            const float4* xp0 = (const float4*)(x + (size_t)r0 * F_IN + 8 * lane);
            const float4* xp1 = (const float4*)(x + (size_t)r1 * F_IN + 8 * lane);
            const float4* xp2 = (const float4*)(x + (size_t)r2 * F_IN + 8 * lane);
            const float4* xp3 = (const float4*)(x + (size_t)r3 * F_IN + 8 * lane);
            float4 a, b;
            a = xp0[0]; b = xp0[1];
            xv[0][0]=a.x; xv[0][1]=a.y; xv[0][2]=a.z; xv[0][3]=a.w;
            xv[0][4]=b.x; xv[0][5]=b.y; xv[0][6]=b.z; xv[0][7]=b.w;
            a = xp1[0]; b = xp1[1];
            xv[1][0]=a.x; xv[1][1]=a.y; xv[1][2]=a.z; xv[1][3]=a.w;
            xv[1][4]=b.x; xv[1][5]=b.y; xv[1][6]=b.z; xv[1][7]=b.w;
            a = xp2[0]; b = xp2[1];
            xv[2][0]=a.x; xv[2][1]=a.y; xv[2][2]=a.z; xv[2][3]=a.w;
            xv[2][4]=b.x; xv[2][5]=b.y; xv[2][6]=b.z; xv[2][7]=b.w;
            a = xp3[0]; b = xp3[1];
            xv[3][0]=a.x; xv[3][1]=a.y; xv[3][2]=a.z; xv[3][3]=a.w;
            xv[3][4]=b.x; xv[3][5]=b.y; xv[3][6]=b.z; xv[3][7]=b.w;
        }

        float acc[4][16];
#pragma unroll
        for (int i = 0; i < 4; ++i)
#pragma unroll
            for (int j = 0; j < 16; ++j) acc[i][j] = 0.f;

#pragma unroll
        for (int kk = 0; kk < 8; ++kk) {
            const float4* wp = (const float4*)(W1 + (size_t)(8 * lane + kk) * HID);
#pragma unroll
            for (int jj = 0; jj < 4; ++jj) {
                float4 t = wp[jj];
#pragma unroll
                for (int i = 0; i < 4; ++i) {
                    float xs = xv[i][kk];
                    acc[i][jj * 4 + 0] += xs * t.x;
                    acc[i][jj * 4 + 1] += xs * t.y;
                    acc[i][jj * 4 + 2] += xs * t.z;
                    acc[i][jj * 4 + 3] += xs * t.w;
                }
            }
        }

        int rr[4] = {r0, r1, r2, r3};
#pragma unroll
        for (int i = 0; i < 4; ++i) {
            float* a = acc[i];
#pragma unroll
            for (int u = 0; u < 8; ++u) {
                float k = s3 ? a[u + 8] : a[u];
                float s = s3 ? a[u] : a[u + 8];
                a[u] = k + __shfl_xor(s, 8);
            }
#pragma unroll
            for (int u = 0; u < 4; ++u) {
                float k = s2 ? a[u + 4] : a[u];
                float s = s2 ? a[u] : a[u + 4];
                a[u] = k + __shfl_xor(s, 4);
            }
#pragma unroll
            for (int u = 0; u < 2; ++u) {
                float k = s1 ? a[u + 2] : a[u];
                float s = s1 ? a[u] : a[u + 2];
                a[u] = k + __shfl_xor(s, 2);
            }
            {
                float k = s0 ? a[1] : a[0];
                float s = s0 ? a[0] : a[1];
                a[0] = k + __shfl_xor(s, 1);
            }
            a[0] += __shfl_xor(a[0], 16);
            a[0] += __shfl_xor(a[0], 32);

            float val = fmaxf(a[0] + bias, 0.f);
            bool live = (g + i < rE);
            if (live && lane < 16) h0[(size_t)rr[i] * HID + lane] = val;

            float qq = val * val;
            qq += __shfl_xor(qq, 1);
            qq += __shfl_xor(qq, 2);
            qq += __shfl_xor(qq, 4);
            qq += __shfl_xor(qq, 8);
            if (live && lane == 0) inv0[rr[i]] = 1.f / fmaxf(sqrtf(qq), 1e-12f);
        }
    }
}

// ---------------------------------------------------------------------------
// CSR build, pass 1: per-block LDS histogram of buckets (bucket = dst>>8).
// ---------------------------------------------------------------------------
__global__ __launch_bounds__(256) void hist1_kernel(
    const int* __restrict__ dst, int E, int EV, int nbuck,
    int* __restrict__ bucketCount)
{
    __shared__ int h[NBUCK_MAX];
    int tid = threadIdx.x;
    for (int j = tid; j < nbuck; j += 256) h[j] = 0;
    __syncthreads();
    int base = blockIdx.x * EPB;
    for (int k = 0; k < EPB / 256; ++k) {
        int i = base + k * 256 + tid;
        if (i < EV) {
            int d = (i < E) ? dst[i] : (i - E);
            atomicAdd(&h[d >> 8], 1);
        }
    }
    __syncthreads();
    for (int j = tid; j < nbuck; j += 256)
        if (h[j]) atomicAdd(&bucketCount[j], h[j]);
}

// ---------------------------------------------------------------------------
// CSR build, pass 2: single-WG exclusive scan of bucket counts.
// ---------------------------------------------------------------------------
__global__ __launch_bounds__(512) void bucket_scan_kernel(
    const int* __restrict__ bucketCount, int nbuck,
    int* __restrict__ bucketStart, int* __restrict__ gCursor)
{
    __shared__ int s[512];
    int t = threadIdx.x;
    int v = (t < nbuck) ? bucketCount[t] : 0;
    s[t] = v;
    __syncthreads();
    for (int off = 1; off < 512; off <<= 1) {
        int add = (t >= off) ? s[t - off] : 0;
        __syncthreads();
        s[t] += add;
        __syncthreads();
    }
    int incl = s[t];
    if (t < nbuck) {
        bucketStart[t] = incl - v;
        gCursor[t]     = incl - v;
        if (t == nbuck - 1) bucketStart[nbuck] = incl;
    }
}

// ---------------------------------------------------------------------------
// CSR pass 3 FUSED with gemm rows [rB,rE): blocks [0,csrBlocks) partition
// edges into bucket regions of `staged`; remaining blocks run gemm. The two
// sides touch disjoint data (src/dst/staged vs x/W1/h0) so they overlap on
// the device instead of serializing on the stream.
// staged entry packs src (17b) | dstLocal (8b) << 17.
// ---------------------------------------------------------------------------
__global__ __launch_bounds__(256) void part_gemm_kernel(
    const int* __restrict__ src, const int* __restrict__ dst,
    int E, int EV, int nbuck, int* __restrict__ gCursor,
    unsigned* __restrict__ staged,
    const float* __restrict__ x, const float* __restrict__ W1,
    const float* __restrict__ b1, float* __restrict__ h0,
    float* __restrict__ inv0, int rB, int rE, int csrBlocks, int gemmWaves)
{
    __shared__ int h[NBUCK_MAX];
    __shared__ int gb[NBUCK_MAX];
    int tid = threadIdx.x;

    if ((int)blockIdx.x >= csrBlocks) {
        int wid = (((int)blockIdx.x - csrBlocks) * 256 + tid) >> 6;
        gemm_rows(x, W1, b1, h0, inv0, rB, rE, wid, gemmWaves, tid & 63);
        return;
    }

    for (int j = tid; j < nbuck; j += 256) h[j] = 0;
    __syncthreads();

    int base = blockIdx.x * EPB;
    // pass A: local histogram
    for (int k = 0; k < EPB / 256; ++k) {
        int i = base + k * 256 + tid;
        if (i < EV) {
            int d = (i < E) ? dst[i] : (i - E);
            atomicAdd(&h[d >> 8], 1);
        }
    }
    __syncthreads();
    // reserve contiguous chunks
    for (int j = tid; j < nbuck; j += 256) {
        int c = h[j];
        if (c) gb[j] = atomicAdd(&gCursor[j], c);
        h[j] = 0;  // reuse as local cursor
    }
    __syncthreads();
    // pass B: re-read edges, write packed entries into reserved chunks
    for (int k = 0; k < EPB / 256; ++k) {
        int i = base + k * 256 + tid;
        if (i < EV) {
            int s, d;
            if (i < E) { s = src[i]; d = dst[i]; }
            else       { s = i - E;  d = s; }
            int bkt = d >> 8;
            int ofs = atomicAdd(&h[bkt], 1);
            staged[gb[bkt] + ofs] = (unsigned)s | ((unsigned)(d & 255) << 17);
        }
    }
}

// ---------------------------------------------------------------------------
// CSR pass 4 FUSED with gemm rows [rB,rE): blocks [0,csrBlocks) build
// counts/rowstart/esrc (one block per bucket); remaining blocks run gemm.
// ---------------------------------------------------------------------------
__global__ __launch_bounds__(256) void build_gemm_kernel(
    const unsigned* __restrict__ staged, const int* __restrict__ bucketStart,
    int* __restrict__ counts, int* __restrict__ rowstart,
    int* __restrict__ esrc, int N,
    const float* __restrict__ x, const float* __restrict__ W1,
    const float* __restrict__ b1, float* __restrict__ h0,
    float* __restrict__ inv0, int rB, int rE, int csrBlocks, int gemmWaves)
{
    __shared__ int hist[256];
    __shared__ int s[256];
    __shared__ int cur[256];
    int tid = threadIdx.x;

    if ((int)blockIdx.x >= csrBlocks) {
        int wid = (((int)blockIdx.x - csrBlocks) * 256 + tid) >> 6;
        gemm_rows(x, W1, b1, h0, inv0, rB, rE, wid, gemmWaves, tid & 63);
        return;
    }

    int b   = blockIdx.x;
    int start = bucketStart[b];
    int end   = bucketStart[b + 1];

    hist[tid] = 0;
    __syncthreads();
    for (int i = start + tid; i < end; i += 256)
        atomicAdd(&hist[(staged[i] >> 17) & 255], 1);
    __syncthreads();

    int v = hist[tid];
    s[tid] = v;
    __syncthreads();
    for (int off = 1; off < 256; off <<= 1) {
        int add = (tid >= off) ? s[tid - off] : 0;
        __syncthreads();
        s[tid] += add;
        __syncthreads();
    }
    int excl = s[tid] - v;
    int dstg = b * 256 + tid;
    if (dstg < N) {
        counts[dstg]   = v;
        rowstart[dstg] = start + excl;
    }
    cur[tid] = start + excl;
    __syncthreads();

    for (int i = start + tid; i < end; i += 256) {
        unsigned pk = staged[i];
        int dl  = (pk >> 17) & 255;
        int pos = atomicAdd(&cur[dl], 1);
        esrc[pos] = (int)(pk & 0x1FFFFu);
    }
}

// ---------------------------------------------------------------------------
// Attention layer: ONE WAVE PER NODE, 4 lanes per edge (q = feature quad,
// e = edge slot 0..15). 4 UNROLLED SLOT GROUPS (64 edges) with all esrc
// loads issued first (1 latency) then all h/inv gathers (1 latency),
// instead of ceil(cnt/16) serial esrc->gather chains. Invalid slots read
// safe index start+0 and contribute w=0. Residual loop only for cnt>64
// (P(Poisson(33) > 63) ~ 1e-8 per node).
// Softmax shift-invariance: constant shift |beta| since cos in [-1,1].
// ---------------------------------------------------------------------------
__global__ __launch_bounds__(256) void agg_kernel(
    const float* __restrict__ h, const float* __restrict__ inv,
    const int* __restrict__ esrc, const int* __restrict__ rowstart,
    const int* __restrict__ counts, const float* __restrict__ beta_p,
    float* __restrict__ hout, float* __restrict__ invout, int N)
{
    int node = (blockIdx.x * blockDim.x + threadIdx.x) >> 6;
    if (node >= N) return;
    int lane = threadIdx.x & 63;
    int q = lane & 3;        // feature quad: features 4q..4q+3
    int e = lane >> 2;       // edge slot 0..15

    float beta  = *beta_p;
    float shift = fabsf(beta);
    float4 hd4  = ((const float4*)(h + (size_t)node * HID))[q];
    float  invd = inv[node];
    int start = rowstart[node];
    int cnt   = counts[node];

    // ---- issue all 4 slot-groups' esrc loads (independent addresses) ----
    int t0 = e, t1 = e + 16, t2 = e + 32, t3 = e + 48;
    int s0 = esrc[start + (t0 < cnt ? t0 : 0)];
    int s1 = esrc[start + (t1 < cnt ? t1 : 0)];
    int s2 = esrc[start + (t2 < cnt ? t2 : 0)];
    int s3 = esrc[start + (t3 < cnt ? t3 : 0)];
    // ---- issue all gathers ----
    const float4* hp = (const float4*)h;
    float4 a0 = hp[(size_t)s0 * 4 + q];
    float4 a1 = hp[(size_t)s1 * 4 + q];
    float4 a2 = hp[(size_t)s2 * 4 + q];
    float4 a3 = hp[(size_t)s3 * 4 + q];
    float i0 = inv[s0], i1 = inv[s1], i2 = inv[s2], i3 = inv[s3];

    float denom = 0.f;
    float4 acc = make_float4(0.f, 0.f, 0.f, 0.f);

#define AGG_SLOT(aa, ii, tt)                                                  \
    {                                                                         \
        float p = aa.x * hd4.x + aa.y * hd4.y + aa.z * hd4.z + aa.w * hd4.w;  \
        p += __shfl_xor(p, 1);                                                \
        p += __shfl_xor(p, 2);                                                \
        float w = __expf(beta * (p * invd * ii) - shift);                     \
        w = (tt < cnt) ? w : 0.f;                                             \
        denom += w;                                                           \
        acc.x += w * aa.x; acc.y += w * aa.y;                                 \
        acc.z += w * aa.z; acc.w += w * aa.w;                                 \
    }
    AGG_SLOT(a0, i0, t0)
    AGG_SLOT(a1, i1, t1)
    AGG_SLOT(a2, i2, t2)
    AGG_SLOT(a3, i3, t3)
#undef AGG_SLOT

    // residual edges (cnt > 64): essentially never taken, kept for correctness
    for (int t = e + 64; t < cnt; t += 16) {
        int sr = esrc[start + t];
        float4 hs4 = hp[(size_t)sr * 4 + q];
        float invs = inv[sr];
        float p = hs4.x * hd4.x + hs4.y * hd4.y + hs4.z * hd4.z + hs4.w * hd4.w;
        p += __shfl_xor(p, 1);
        p += __shfl_xor(p, 2);
        float w = __expf(beta * (p * invd * invs) - shift);
        denom += w;
        acc.x += w * hs4.x;
        acc.y += w * hs4.y;
        acc.z += w * hs4.z;
        acc.w += w * hs4.w;
    }

    // reduce across the 16 edge slots (lane bits 2..5)
#pragma unroll
    for (int off = 4; off <= 32; off <<= 1) {
        denom += __shfl_xor(denom, off);
        acc.x += __shfl_xor(acc.x, off);
        acc.y += __shfl_xor(acc.y, off);
        acc.z += __shfl_xor(acc.z, off);
        acc.w += __shfl_xor(acc.w, off);
    }
    float rd = 1.f / denom;        // denom>0 guaranteed by self-loop
    float4 o = make_float4(acc.x * rd, acc.y * rd, acc.z * rd, acc.w * rd);
    if (lane < 4) ((float4*)(hout + (size_t)node * HID))[q] = o;

    float ss = o.x * o.x + o.y * o.y + o.z * o.z + o.w * o.w;
    ss += __shfl_xor(ss, 1);
    ss += __shfl_xor(ss, 2);
    if (lane == 0) invout[node] = 1.f / fmaxf(sqrtf(ss), 1e-12f);
}

// ---------------------------------------------------------------------------
// K5: out = log_softmax(h2 @ W2 + b2). One wave per row, lane = class.
// ---------------------------------------------------------------------------
__global__ __launch_bounds__(256) void out_kernel(
    const float* __restrict__ h2, const float* __restrict__ W2,
    const float* __restrict__ b2, float* __restrict__ out, int N)
{
    int wave = (blockIdx.x * blockDim.x + threadIdx.x) >> 6;
    int lane = threadIdx.x & 63;
    if (wave >= N) return;

    float hv = (lane < HID) ? h2[(size_t)wave * HID + lane] : 0.f;
    float acc = b2[lane];
#pragma unroll
    for (int k = 0; k < HID; ++k) {
        float hk = __shfl(hv, k);
        acc += hk * W2[k * NCLS + lane];
    }
    float m = acc;
    for (int off = 32; off > 0; off >>= 1) m = fmaxf(m, __shfl_xor(m, off));
    float e = __expf(acc - m);
    float ssum = e;
    for (int off = 32; off > 0; off >>= 1) ssum += __shfl_xor(ssum, off);
    out[(size_t)wave * NCLS + lane] = (acc - m) - __logf(ssum);
}

// ---------------------------------------------------------------------------
extern "C" void kernel_launch(void* const* d_in, const int* in_sizes, int n_in,
                              void* d_out, int out_size, void* d_ws, size_t ws_size,
                              hipStream_t stream)
{
    const float* x     = (const float*)d_in[0];
    const int*   eidx  = (const int*)d_in[1];
    const float* W1    = (const float*)d_in[2];
    const float* b1    = (const float*)d_in[3];
    const float* W2    = (const float*)d_in[4];
    const float* b2    = (const float*)d_in[5];
    const float* beta1 = (const float*)d_in[6];
    const float* beta2 = (const float*)d_in[7];

    int N = in_sizes[0] / F_IN;       // 100000
    int E = in_sizes[1] / 2;          // 3200000
    const int* src = eidx;
    const int* dst = eidx + E;
    float* out = (float*)d_out;

    int EV    = E + N;                // virtual edges (incl. self-loops)
    int nbuck = (N + 255) / 256;      // 391

    char* wptr = (char*)d_ws;
    auto alloc = [&](size_t bytes) -> char* {
        char* p = wptr;
        wptr += (bytes + 255) / 256 * 256;
        return p;
    };
    float*    h0       = (float*)alloc((size_t)N * HID * 4);
    float*    inv0     = (float*)alloc((size_t)N * 4);
    float*    h1       = (float*)alloc((size_t)N * HID * 4);
    float*    inv1     = (float*)alloc((size_t)N * 4);
    float*    h2       = (float*)alloc((size_t)N * HID * 4);
    float*    inv2     = (float*)alloc((size_t)N * 4);
    int*      counts   = (int*)alloc((size_t)N * 4);
    int*      rowstart = (int*)alloc((size_t)(N + 1) * 4);
    int*      esrc     = (int*)alloc((size_t)EV * 4);
    unsigned* staged   = (unsigned*)alloc((size_t)EV * 4);
    int*      bucketCount = (int*)alloc((size_t)(nbuck + 1) * 4);
    int*      bucketStart = (int*)alloc((size_t)(nbuck + 1) * 4);
    int*      gCursor     = (int*)alloc((size_t)nbuck * 4);

    int ebBlocks = (EV + EPB - 1) / EPB;  // 403

    // CSR build front (tiny): hist + scan
    hipMemsetAsync(bucketCount, 0, (size_t)nbuck * 4, stream);
    hist1_kernel<<<ebBlocks, 256, 0, stream>>>(dst, E, EV, nbuck, bucketCount);
    bucket_scan_kernel<<<1, 512, 0, stream>>>(bucketCount, nbuck, bucketStart, gCursor);

    // partition + gemm rows [0, rSplit) overlapped in one launch;
    // build_csr + gemm rows [rSplit, N) in the next. CSR blocks come first
    // in dispatch order so the CSR chain isn't delayed.
    int rSplit   = 60000;
    int gcBlocks = 1024;   // 4096 gemm waves alongside partition
    int gdBlocks = 768;    // 3072 gemm waves alongside build_csr
    part_gemm_kernel<<<ebBlocks + gcBlocks, 256, 0, stream>>>(
        src, dst, E, EV, nbuck, gCursor, staged,
        x, W1, b1, h0, inv0, 0, rSplit, ebBlocks, gcBlocks * 4);
    build_gemm_kernel<<<nbuck + gdBlocks, 256, 0, stream>>>(
        staged, bucketStart, counts, rowstart, esrc, N,
        x, W1, b1, h0, inv0, rSplit, N, nbuck, gdBlocks * 4);

    // two attention layers: one wave per node
    int aggBlocks = (N + 3) / 4;   // 4 waves (nodes) per 256-thread block
    agg_kernel<<<aggBlocks, 256, 0, stream>>>(h0, inv0, esrc, rowstart, counts, beta1,
                                              h1, inv1, N);
    agg_kernel<<<aggBlocks, 256, 0, stream>>>(h1, inv1, esrc, rowstart, counts, beta2,
                                              h2, inv2, N);

    // out = log_softmax(h2@W2+b2)
    out_kernel<<<(N * 64 + 255) / 256, 256, 0, stream>>>(h2, W2, b2, out, N);
}